// Round 1
// baseline (3085.273 us; speedup 1.0000x reference)
//
#include <hip/hip_runtime.h>
#include <hip/hip_bf16.h>
#include <math.h>

// Problem constants (from reference)
#define BB 2
#define HH 56
#define WW 56
#define LL (HH*WW)          // 3136
#define CM 96               // D_MODEL
#define DI 192              // D_INNER
#define NS 16               // D_STATE
#define NPIX (BB*LL)        // 6272
#define PROJ2 (2*DI)        // 384
#define SSMW (2*NS+1)       // 33
#define SSMW4 (4*SSMW)      // 132

__device__ __forceinline__ float sigmoidf_(float v) { return 1.f / (1.f + __expf(-v)); }

// ---------------- Kernel A: LayerNorm + in_proj (96 -> 384), split into xproj / silu(z)
__global__ __launch_bounds__(128) void k_ln_inproj(
    const float* __restrict__ x, const float* __restrict__ g, const float* __restrict__ bta,
    const float* __restrict__ W, float* __restrict__ xproj, float* __restrict__ siluz)
{
    int pix = blockIdx.x;
    int t = threadIdx.x;
    __shared__ float xn[CM];
    __shared__ float red[128];

    float v = (t < CM) ? x[(size_t)pix*CM + t] : 0.f;
    red[t] = v; __syncthreads();
    #pragma unroll
    for (int s = 64; s > 0; s >>= 1) { if (t < s) red[t] += red[t+s]; __syncthreads(); }
    float mu = red[0] * (1.f/CM);
    __syncthreads();
    float dv = (t < CM) ? (v - mu) : 0.f;
    red[t] = dv*dv; __syncthreads();
    #pragma unroll
    for (int s = 64; s > 0; s >>= 1) { if (t < s) red[t] += red[t+s]; __syncthreads(); }
    float var = red[0] * (1.f/CM);
    float rstd = rsqrtf(var + 1e-5f);
    if (t < CM) xn[t] = (v - mu) * rstd * g[t] + bta[t];
    __syncthreads();

    float a0 = 0.f, a1 = 0.f, a2 = 0.f;
    #pragma unroll 4
    for (int c = 0; c < CM; ++c) {
        float xv = xn[c];
        const float* Wr = W + (size_t)c*PROJ2;
        a0 = fmaf(xv, Wr[t      ], a0);
        a1 = fmaf(xv, Wr[t + 128], a1);
        a2 = fmaf(xv, Wr[t + 256], a2);
    }
    // o = t (<128: xproj), t+128 (mixed), t+256 (z)
    xproj[(size_t)pix*DI + t] = a0;
    int o1 = t + 128;
    if (o1 < DI) xproj[(size_t)pix*DI + o1] = a1;
    else         siluz[(size_t)pix*DI + (o1 - DI)] = a1 * sigmoidf_(a1);
    int o2 = t + 256;
    siluz[(size_t)pix*DI + (o2 - DI)] = a2 * sigmoidf_(a2);
}

// ---------------- Kernel B: depthwise 3x3 conv + bias + SiLU  (NHWC, zero pad)
__global__ __launch_bounds__(DI) void k_conv(
    const float* __restrict__ xproj, const float* __restrict__ cw, const float* __restrict__ cb,
    float* __restrict__ xc)
{
    int pix = blockIdx.x;
    int b = pix / LL; int p = pix % LL;
    int h = p / WW, w = p % WW;
    int c = threadIdx.x;
    float acc = cb[c];
    #pragma unroll
    for (int dh = -1; dh <= 1; ++dh) {
        int hh = h + dh; if (hh < 0 || hh >= HH) continue;
        #pragma unroll
        for (int dw = -1; dw <= 1; ++dw) {
            int ww = w + dw; if (ww < 0 || ww >= WW) continue;
            acc = fmaf(xproj[((size_t)(b*LL + hh*WW + ww))*DI + c],
                       cw[c*9 + (dh+1)*3 + (dw+1)], acc);
        }
    }
    xc[(size_t)pix*DI + c] = acc * sigmoidf_(acc);
}

// ---------------- Kernel C: ssm projection  xc(192) @ x_proj_w(192,132) -> ssm(132)
__global__ __launch_bounds__(DI) void k_xproj(
    const float* __restrict__ xc, const float* __restrict__ W2, float* __restrict__ ssm)
{
    int pix = blockIdx.x; int t = threadIdx.x;
    __shared__ float xv[DI];
    xv[t] = xc[(size_t)pix*DI + t];
    __syncthreads();
    if (t < SSMW4) {
        float acc = 0.f;
        #pragma unroll 4
        for (int c = 0; c < DI; ++c) acc = fmaf(xv[c], W2[(size_t)c*SSMW4 + t], acc);
        ssm[(size_t)pix*SSMW4 + t] = acc;
    }
}

// ---------------- Kernel E: 4-direction selective scan
// grid = 4 dirs * 2 batch * 3 channel-chunks = 24 blocks of 64 threads.
// Each thread owns one channel d, holds h[16] in registers.
__global__ __launch_bounds__(64) void k_scan(
    const float* __restrict__ ssm, const float* __restrict__ xc,
    const float* __restrict__ A_log, const float* __restrict__ dt_w,
    const float* __restrict__ dt_b, const float* __restrict__ Ds,
    float* __restrict__ yacc)
{
    int idx = blockIdx.x;             // 0..23
    int k = idx / 6;                  // direction
    int b = (idx % 6) / 3;            // batch
    int chunk = idx % 3;
    int d = chunk * 64 + threadIdx.x; // channel

    float negA[NS];
    #pragma unroll
    for (int n = 0; n < NS; ++n) negA[n] = -__expf(A_log[d*NS + n]);
    float dtw = dt_w[k*DI + d];
    float dtb = dt_b[k*DI + d];
    float Dk  = Ds[k*DI + d];

    float h[NS];
    #pragma unroll
    for (int n = 0; n < NS; ++n) h[n] = 0.f;

    const float* ssmb = ssm + (size_t)b*LL*SSMW4 + 33*k;
    const float* xcb  = xc  + (size_t)b*LL*DI;
    float* yb = yacc + (size_t)b*LL*DI;

    for (int l = 0; l < LL; ++l) {
        int j;
        if (k == 0)      j = l;
        else if (k == 1) j = LL - 1 - l;
        else {
            int l2 = (k == 2) ? l : (LL - 1 - l);
            j = (l2 % HH) * WW + (l2 / HH);   // column-major <-> row-major remap
        }
        const float* row = ssmb + (size_t)l*SSMW4;
        float d0 = row[0];
        float pre = fmaf(d0, dtw, dtb);
        // stable softplus: max(x,0) + log1p(exp(-|x|))
        float dt = fmaxf(pre, 0.f) + log1pf(__expf(-fabsf(pre)));
        float xt = xcb[(size_t)j*DI + d];
        float dx = dt * xt;
        float y = 0.f;
        #pragma unroll
        for (int n = 0; n < NS; ++n) {
            float Bn = row[1 + n];
            float Cn = row[17 + n];
            float dA = __expf(dt * negA[n]);
            h[n] = fmaf(dA, h[n], dx * Bn);
            y = fmaf(h[n], Cn, y);
        }
        y = fmaf(xt, Dk, y);
        atomicAdd(&yb[(size_t)j*DI + d], y);
    }
}

// ---------------- Kernel F: gate with silu(z), out_proj (192->96), + residual
__global__ __launch_bounds__(DI) void k_out(
    const float* __restrict__ yacc, const float* __restrict__ siluz,
    const float* __restrict__ Wout, const float* __restrict__ x,
    float* __restrict__ out)
{
    int pix = blockIdx.x; int t = threadIdx.x;
    __shared__ float prod[DI];
    prod[t] = yacc[(size_t)pix*DI + t] * siluz[(size_t)pix*DI + t];
    __syncthreads();
    if (t < CM) {
        float acc = x[(size_t)pix*CM + t];
        #pragma unroll 4
        for (int c = 0; c < DI; ++c) acc = fmaf(prod[c], Wout[(size_t)c*CM + t], acc);
        out[(size_t)pix*CM + t] = acc;
    }
}

extern "C" void kernel_launch(void* const* d_in, const int* in_sizes, int n_in,
                              void* d_out, int out_size, void* d_ws, size_t ws_size,
                              hipStream_t stream) {
    const float* x        = (const float*)d_in[0];
    const float* ln_g     = (const float*)d_in[1];
    const float* ln_b     = (const float*)d_in[2];
    const float* in_projw = (const float*)d_in[3];
    const float* conv_w   = (const float*)d_in[4];
    const float* conv_b   = (const float*)d_in[5];
    const float* x_projw  = (const float*)d_in[6];
    const float* dt_w     = (const float*)d_in[7];
    const float* dt_b     = (const float*)d_in[8];
    const float* A_log    = (const float*)d_in[9];
    const float* Ds       = (const float*)d_in[10];
    const float* out_projw= (const float*)d_in[11];
    float* out = (float*)d_out;

    // workspace layout (floats)
    float* ws = (float*)d_ws;
    size_t n192 = (size_t)NPIX * DI;       // 1,204,224
    size_t n132 = (size_t)NPIX * SSMW4;    // 827,904
    float* xproj = ws;                      // later reused as yacc
    float* siluz = ws + n192;
    float* xc    = ws + 2*n192;
    float* ssm   = ws + 3*n192;
    float* yacc  = xproj;                   // reuse after conv

    k_ln_inproj<<<NPIX, 128, 0, stream>>>(x, ln_g, ln_b, in_projw, xproj, siluz);
    k_conv<<<NPIX, DI, 0, stream>>>(xproj, conv_w, conv_b, xc);
    k_xproj<<<NPIX, DI, 0, stream>>>(xc, x_projw, ssm);
    hipMemsetAsync(yacc, 0, n192 * sizeof(float), stream);
    k_scan<<<24, 64, 0, stream>>>(ssm, xc, A_log, dt_w, dt_b, Ds, yacc);
    k_out<<<NPIX, DI, 0, stream>>>(yacc, siluz, out_projw, x, out);
}

// Round 2
// 320.945 us; speedup vs baseline: 9.6131x; 9.6131x over previous
//
#include <hip/hip_runtime.h>
#include <hip/hip_bf16.h>
#include <math.h>

// Problem constants (from reference)
#define BB 2
#define HH 56
#define WW 56
#define LL (HH*WW)          // 3136
#define CM 96               // D_MODEL
#define DI 192              // D_INNER
#define NS 16               // D_STATE
#define NPIX (BB*LL)        // 6272
#define PROJ2 (2*DI)        // 384
#define SSMW (2*NS+1)       // 33
#define SSMW4 (4*SSMW)      // 132

// chunked scan decomposition: 3136 = NC * LC
#define NC 98
#define LC 32

__device__ __forceinline__ float sigmoidf_(float v) { return 1.f / (1.f + __expf(-v)); }

__device__ __forceinline__ int dir_map(int k, int l) {
    if (k == 0) return l;
    if (k == 1) return LL - 1 - l;
    int l2 = (k == 2) ? l : (LL - 1 - l);
    return (l2 % HH) * WW + (l2 / HH);   // column-major <-> row-major remap
}

// ---------------- Kernel A: LayerNorm + in_proj (96 -> 384), split into xproj / silu(z)
__global__ __launch_bounds__(128) void k_ln_inproj(
    const float* __restrict__ x, const float* __restrict__ g, const float* __restrict__ bta,
    const float* __restrict__ W, float* __restrict__ xproj, float* __restrict__ siluz)
{
    int pix = blockIdx.x;
    int t = threadIdx.x;
    __shared__ float xn[CM];
    __shared__ float red[128];

    float v = (t < CM) ? x[(size_t)pix*CM + t] : 0.f;
    red[t] = v; __syncthreads();
    #pragma unroll
    for (int s = 64; s > 0; s >>= 1) { if (t < s) red[t] += red[t+s]; __syncthreads(); }
    float mu = red[0] * (1.f/CM);
    __syncthreads();
    float dv = (t < CM) ? (v - mu) : 0.f;
    red[t] = dv*dv; __syncthreads();
    #pragma unroll
    for (int s = 64; s > 0; s >>= 1) { if (t < s) red[t] += red[t+s]; __syncthreads(); }
    float var = red[0] * (1.f/CM);
    float rstd = rsqrtf(var + 1e-5f);
    if (t < CM) xn[t] = (v - mu) * rstd * g[t] + bta[t];
    __syncthreads();

    float a0 = 0.f, a1 = 0.f, a2 = 0.f;
    #pragma unroll 4
    for (int c = 0; c < CM; ++c) {
        float xv = xn[c];
        const float* Wr = W + (size_t)c*PROJ2;
        a0 = fmaf(xv, Wr[t      ], a0);
        a1 = fmaf(xv, Wr[t + 128], a1);
        a2 = fmaf(xv, Wr[t + 256], a2);
    }
    xproj[(size_t)pix*DI + t] = a0;
    int o1 = t + 128;
    if (o1 < DI) xproj[(size_t)pix*DI + o1] = a1;
    else         siluz[(size_t)pix*DI + (o1 - DI)] = a1 * sigmoidf_(a1);
    int o2 = t + 256;
    siluz[(size_t)pix*DI + (o2 - DI)] = a2 * sigmoidf_(a2);
}

// ---------------- Kernel B: depthwise 3x3 conv + bias + SiLU  (NHWC, zero pad)
__global__ __launch_bounds__(DI) void k_conv(
    const float* __restrict__ xproj, const float* __restrict__ cw, const float* __restrict__ cb,
    float* __restrict__ xc)
{
    int pix = blockIdx.x;
    int b = pix / LL; int p = pix % LL;
    int h = p / WW, w = p % WW;
    int c = threadIdx.x;
    float acc = cb[c];
    #pragma unroll
    for (int dh = -1; dh <= 1; ++dh) {
        int hh = h + dh; if (hh < 0 || hh >= HH) continue;
        #pragma unroll
        for (int dw = -1; dw <= 1; ++dw) {
            int ww = w + dw; if (ww < 0 || ww >= WW) continue;
            acc = fmaf(xproj[((size_t)(b*LL + hh*WW + ww))*DI + c],
                       cw[c*9 + (dh+1)*3 + (dw+1)], acc);
        }
    }
    xc[(size_t)pix*DI + c] = acc * sigmoidf_(acc);
}

// ---------------- Kernel C: ssm projection  xc(192) @ x_proj_w(192,132) -> ssm(132)
__global__ __launch_bounds__(DI) void k_xproj(
    const float* __restrict__ xc, const float* __restrict__ W2, float* __restrict__ ssm)
{
    int pix = blockIdx.x; int t = threadIdx.x;
    __shared__ float xv[DI];
    xv[t] = xc[(size_t)pix*DI + t];
    __syncthreads();
    if (t < SSMW4) {
        float acc = 0.f;
        #pragma unroll 4
        for (int c = 0; c < DI; ++c) acc = fmaf(xv[c], W2[(size_t)c*SSMW4 + t], acc);
        ssm[(size_t)pix*SSMW4 + t] = acc;
    }
}

// ---------------- Scan phase 1: per-chunk local scan (h_in = 0), store H[16] and sum(dt)
// grid = 4 dirs * 2 batch * NC chunks; block = 192 (one thread per channel)
__global__ __launch_bounds__(DI) void k_scan1(
    const float* __restrict__ ssm, const float* __restrict__ xc,
    const float* __restrict__ A_log, const float* __restrict__ dt_w,
    const float* __restrict__ dt_b,
    float* __restrict__ Hbuf, float* __restrict__ sdbuf)
{
    int idx = blockIdx.x;          // ((k*2+b)*NC + c)
    int c  = idx % NC;
    int kb = idx / NC;
    int b = kb & 1;
    int k = kb >> 1;
    int d = threadIdx.x;

    float negA[NS];
    #pragma unroll
    for (int n = 0; n < NS; ++n) negA[n] = -__expf(A_log[d*NS + n]);
    float dtw = dt_w[k*DI + d];
    float dtb = dt_b[k*DI + d];

    float h[NS];
    #pragma unroll
    for (int n = 0; n < NS; ++n) h[n] = 0.f;
    float sumdt = 0.f;

    const float* ssmb = ssm + (size_t)b*LL*SSMW4 + 33*k;
    const float* xcb  = xc  + (size_t)b*LL*DI;
    int l0 = c * LC;

    for (int li = 0; li < LC; ++li) {
        int l = l0 + li;
        int j = dir_map(k, l);
        const float* row = ssmb + (size_t)l*SSMW4;
        float pre = fmaf(row[0], dtw, dtb);
        float dt = fmaxf(pre, 0.f) + log1pf(__expf(-fabsf(pre)));
        sumdt += dt;
        float xt = xcb[(size_t)j*DI + d];
        float dx = dt * xt;
        #pragma unroll
        for (int n = 0; n < NS; ++n) {
            float dA = __expf(dt * negA[n]);
            h[n] = fmaf(dA, h[n], dx * row[1 + n]);
        }
    }
    float* Hp = Hbuf + ((size_t)idx*DI + d)*NS;
    #pragma unroll
    for (int n = 0; n < NS; ++n) Hp[n] = h[n];
    sdbuf[(size_t)idx*DI + d] = sumdt;
}

// ---------------- Scan phase 2: exclusive prefix across chunks per (k,b,d,n)
// S_c = incoming state for chunk c; P_c = exp(negA * sumdt_c)
__global__ __launch_bounds__(256) void k_scan2(
    const float* __restrict__ Hbuf, const float* __restrict__ sdbuf,
    const float* __restrict__ A_log, float* __restrict__ Sbuf)
{
    int t = blockIdx.x * 256 + threadIdx.x;  // < 4*2*DI*NS = 24576
    int n = t & (NS-1);
    int d = (t >> 4) % DI;
    int kb = t / (DI*NS);
    float negA = -__expf(A_log[d*NS + n]);
    float s = 0.f;
    for (int c = 0; c < NC; ++c) {
        size_t idx = (size_t)kb*NC + c;
        size_t off = (idx*DI + d)*NS + n;
        Sbuf[off] = s;
        float P = __expf(negA * sdbuf[idx*DI + d]);
        s = fmaf(P, s, Hbuf[off]);
    }
}

// ---------------- Scan phase 3: re-scan chunk from incoming state, write y per direction
__global__ __launch_bounds__(DI) void k_scan3(
    const float* __restrict__ ssm, const float* __restrict__ xc,
    const float* __restrict__ A_log, const float* __restrict__ dt_w,
    const float* __restrict__ dt_b, const float* __restrict__ Ds,
    const float* __restrict__ Sbuf, float* __restrict__ ybuf)
{
    int idx = blockIdx.x;
    int c  = idx % NC;
    int kb = idx / NC;
    int b = kb & 1;
    int k = kb >> 1;
    int d = threadIdx.x;

    float negA[NS];
    #pragma unroll
    for (int n = 0; n < NS; ++n) negA[n] = -__expf(A_log[d*NS + n]);
    float dtw = dt_w[k*DI + d];
    float dtb = dt_b[k*DI + d];
    float Dk  = Ds[k*DI + d];

    float h[NS];
    const float* Sp = Sbuf + ((size_t)idx*DI + d)*NS;
    #pragma unroll
    for (int n = 0; n < NS; ++n) h[n] = Sp[n];

    const float* ssmb = ssm + (size_t)b*LL*SSMW4 + 33*k;
    const float* xcb  = xc  + (size_t)b*LL*DI;
    float* yb = ybuf + ((size_t)k*BB + b)*LL*DI;   // per-direction output
    int l0 = c * LC;

    for (int li = 0; li < LC; ++li) {
        int l = l0 + li;
        int j = dir_map(k, l);
        const float* row = ssmb + (size_t)l*SSMW4;
        float pre = fmaf(row[0], dtw, dtb);
        float dt = fmaxf(pre, 0.f) + log1pf(__expf(-fabsf(pre)));
        float xt = xcb[(size_t)j*DI + d];
        float dx = dt * xt;
        float y = 0.f;
        #pragma unroll
        for (int n = 0; n < NS; ++n) {
            float dA = __expf(dt * negA[n]);
            h[n] = fmaf(dA, h[n], dx * row[1 + n]);
            y = fmaf(h[n], row[17 + n], y);
        }
        y = fmaf(xt, Dk, y);
        yb[(size_t)j*DI + d] = y;     // each (k,b,j,d) written exactly once
    }
}

// ---------------- Kernel F: sum 4 directions, gate with silu(z), out_proj, + residual
__global__ __launch_bounds__(DI) void k_out(
    const float* __restrict__ ybuf, const float* __restrict__ siluz,
    const float* __restrict__ Wout, const float* __restrict__ x,
    float* __restrict__ out)
{
    int pix = blockIdx.x; int t = threadIdx.x;
    int b = pix / LL;
    size_t i = (size_t)pix*DI + t;
    size_t stride = (size_t)BB*LL*DI;
    size_t ib = (size_t)b*LL*DI + (size_t)(pix % LL)*DI + t;
    __shared__ float prod[DI];
    float ysum = ybuf[ib] + ybuf[ib + stride] + ybuf[ib + 2*stride] + ybuf[ib + 3*stride];
    prod[t] = ysum * siluz[i];
    __syncthreads();
    if (t < CM) {
        float acc = x[(size_t)pix*CM + t];
        #pragma unroll 4
        for (int c = 0; c < DI; ++c) acc = fmaf(prod[c], Wout[(size_t)c*CM + t], acc);
        out[(size_t)pix*CM + t] = acc;
    }
}

extern "C" void kernel_launch(void* const* d_in, const int* in_sizes, int n_in,
                              void* d_out, int out_size, void* d_ws, size_t ws_size,
                              hipStream_t stream) {
    const float* x        = (const float*)d_in[0];
    const float* ln_g     = (const float*)d_in[1];
    const float* ln_b     = (const float*)d_in[2];
    const float* in_projw = (const float*)d_in[3];
    const float* conv_w   = (const float*)d_in[4];
    const float* conv_b   = (const float*)d_in[5];
    const float* x_projw  = (const float*)d_in[6];
    const float* dt_w     = (const float*)d_in[7];
    const float* dt_b     = (const float*)d_in[8];
    const float* A_log    = (const float*)d_in[9];
    const float* Ds       = (const float*)d_in[10];
    const float* out_projw= (const float*)d_in[11];
    float* out = (float*)d_out;

    // workspace layout (floats)
    float* ws = (float*)d_ws;
    size_t n192 = (size_t)NPIX * DI;          // 1,204,224
    size_t n132 = (size_t)NPIX * SSMW4;       // 827,904
    size_t nchk = (size_t)4*BB*NC*DI;         // 150,528 (per-chunk, per-channel)
    float* xproj = ws;
    float* siluz = xproj + n192;
    float* xc    = siluz + n192;
    float* ssm   = xc + n192;
    float* ybuf  = ssm + n132;                // 4 * n192
    float* Hbuf  = ybuf + 4*n192;             // nchk * NS
    float* Sbuf  = Hbuf + nchk*NS;            // nchk * NS
    float* sdbuf = Sbuf + nchk*NS;            // nchk

    k_ln_inproj<<<NPIX, 128, 0, stream>>>(x, ln_g, ln_b, in_projw, xproj, siluz);
    k_conv<<<NPIX, DI, 0, stream>>>(xproj, conv_w, conv_b, xc);
    k_xproj<<<NPIX, DI, 0, stream>>>(xc, x_projw, ssm);
    k_scan1<<<4*BB*NC, DI, 0, stream>>>(ssm, xc, A_log, dt_w, dt_b, Hbuf, sdbuf);
    k_scan2<<<(4*BB*DI*NS)/256, 256, 0, stream>>>(Hbuf, sdbuf, A_log, Sbuf);
    k_scan3<<<4*BB*NC, DI, 0, stream>>>(ssm, xc, A_log, dt_w, dt_b, Ds, Sbuf, ybuf);
    k_out<<<NPIX, DI, 0, stream>>>(ybuf, siluz, out_projw, x, out);
}

// Round 4
// 270.316 us; speedup vs baseline: 11.4136x; 1.1873x over previous
//
#include <hip/hip_runtime.h>
#include <hip/hip_bf16.h>
#include <math.h>

// Problem constants (from reference)
#define BB 2
#define HH 56
#define WW 56
#define LL (HH*WW)          // 3136
#define CM 96               // D_MODEL
#define DI 192              // D_INNER
#define NS 16               // D_STATE
#define NPIX (BB*LL)        // 6272
#define PROJ2 (2*DI)        // 384
#define SSMW (2*NS+1)       // 33
#define SSMW4 (4*SSMW)      // 132

// chunked scan decomposition: 3136 = NC * LC
#define NC 196
#define LC 16

__device__ __forceinline__ float sigmoidf_(float v) { return 1.f / (1.f + __expf(-v)); }

__device__ __forceinline__ int dir_map(int k, int l) {
    if (k == 0) return l;
    if (k == 1) return LL - 1 - l;
    int l2 = (k == 2) ? l : (LL - 1 - l);
    return (l2 % HH) * WW + (l2 / HH);   // column-major <-> row-major remap
}

// ---------------- Kernel A: LayerNorm + in_proj (96 -> 384), 8 pixels/block
__global__ __launch_bounds__(384) void k_ln_inproj(
    const float* __restrict__ x, const float* __restrict__ g, const float* __restrict__ bta,
    const float* __restrict__ W, float* __restrict__ xproj, float* __restrict__ siluz)
{
    int pix0 = blockIdx.x * 8;
    int t = threadIdx.x;
    __shared__ float xs[768];          // 8 x 96
    #pragma unroll
    for (int i = t; i < 768; i += 384) xs[i] = x[(size_t)pix0*CM + i];
    __syncthreads();
    if (t < 256) {
        int p = t >> 5, lane = t & 31;
        float v0 = xs[p*96+lane], v1 = xs[p*96+lane+32], v2 = xs[p*96+lane+64];
        float s = v0 + v1 + v2;
        #pragma unroll
        for (int o = 16; o; o >>= 1) s += __shfl_xor(s, o, 32);
        float mu = s * (1.f/96.f);
        float d0 = v0-mu, d1 = v1-mu, d2 = v2-mu;
        float q = d0*d0 + d1*d1 + d2*d2;
        #pragma unroll
        for (int o = 16; o; o >>= 1) q += __shfl_xor(q, o, 32);
        float rstd = rsqrtf(q*(1.f/96.f) + 1e-5f);
        xs[p*96+lane]    = d0*rstd*g[lane]    + bta[lane];
        xs[p*96+lane+32] = d1*rstd*g[lane+32] + bta[lane+32];
        xs[p*96+lane+64] = d2*rstd*g[lane+64] + bta[lane+64];
    }
    __syncthreads();
    float acc[8] = {0.f,0.f,0.f,0.f,0.f,0.f,0.f,0.f};
    for (int c = 0; c < CM; ++c) {
        float w = W[(size_t)c*PROJ2 + t];
        #pragma unroll
        for (int p = 0; p < 8; ++p) acc[p] = fmaf(xs[p*96+c], w, acc[p]);
    }
    if (t < DI) {
        #pragma unroll
        for (int p = 0; p < 8; ++p) xproj[(size_t)(pix0+p)*DI + t] = acc[p];
    } else {
        int o = t - DI;
        #pragma unroll
        for (int p = 0; p < 8; ++p) { float v = acc[p]; siluz[(size_t)(pix0+p)*DI + o] = v * sigmoidf_(v); }
    }
}

// ---------------- Kernel B: depthwise 3x3 conv + bias + SiLU, 8-wide tile with LDS halo
__global__ __launch_bounds__(DI) void k_conv(
    const float* __restrict__ xproj, const float* __restrict__ cw, const float* __restrict__ cb,
    float* __restrict__ xc)
{
    int blk = blockIdx.x;                  // b*HH*7 + h*7 + wq
    int wq = blk % 7; int rest = blk / 7;
    int h = rest % HH; int b = rest / HH;
    int w0 = wq * 8;
    int t = threadIdx.x;                   // channel
    __shared__ float xs[3][10][DI];
    for (int i = t; i < 3*10*DI; i += DI) {
        int c = i % DI; int col = (i/DI) % 10; int row = i / (10*DI);
        int hh = h - 1 + row, ww = w0 - 1 + col;
        float v = 0.f;
        if (hh >= 0 && hh < HH && ww >= 0 && ww < WW)
            v = xproj[((size_t)(b*LL + hh*WW + ww))*DI + c];
        xs[row][col][c] = v;
    }
    __syncthreads();
    float wgt[9];
    #pragma unroll
    for (int q = 0; q < 9; ++q) wgt[q] = cw[t*9 + q];
    float bias = cb[t];
    #pragma unroll
    for (int dw = 0; dw < 8; ++dw) {
        float acc = bias;
        #pragma unroll
        for (int r = 0; r < 3; ++r)
            #pragma unroll
            for (int cc = 0; cc < 3; ++cc)
                acc = fmaf(xs[r][dw+cc][t], wgt[r*3+cc], acc);
        xc[((size_t)(b*LL + h*WW + w0 + dw))*DI + t] = acc * sigmoidf_(acc);
    }
}

// ---------------- Kernel C: ssm projection  xc(192) @ x_proj_w(192,132), 8 pixels/block
__global__ __launch_bounds__(256) void k_xproj(
    const float* __restrict__ xc, const float* __restrict__ W2, float* __restrict__ ssm)
{
    int pix0 = blockIdx.x * 8;
    int t = threadIdx.x;
    __shared__ float xs[8*DI];
    for (int i = t; i < 8*DI; i += 256) xs[i] = xc[(size_t)pix0*DI + i];
    __syncthreads();
    if (t < SSMW4) {
        float acc[8] = {0.f,0.f,0.f,0.f,0.f,0.f,0.f,0.f};
        for (int c = 0; c < DI; ++c) {
            float w = W2[(size_t)c*SSMW4 + t];
            #pragma unroll
            for (int p = 0; p < 8; ++p) acc[p] = fmaf(xs[p*DI+c], w, acc[p]);
        }
        #pragma unroll
        for (int p = 0; p < 8; ++p) ssm[(size_t)(pix0+p)*SSMW4 + t] = acc[p];
    }
}

// ---------------- Scan phase 1: per-chunk local scan (h_in = 0), store H[16] and sum(dt)
__global__ __launch_bounds__(DI) void k_scan1(
    const float* __restrict__ ssm, const float* __restrict__ xc,
    const float* __restrict__ A_log, const float* __restrict__ dt_w,
    const float* __restrict__ dt_b,
    float* __restrict__ Hbuf, float* __restrict__ sdbuf)
{
    int idx = blockIdx.x;          // ((k*2+b)*NC + c)
    int c  = idx % NC;
    int kb = idx / NC;
    int b = kb & 1;
    int k = kb >> 1;
    int d = threadIdx.x;

    __shared__ float rows[LC*SSMW];
    const float* ssmb = ssm + (size_t)b*LL*SSMW4 + SSMW*k;
    int l0 = c * LC;
    for (int i = d; i < LC*SSMW; i += DI) {
        int r = i / SSMW, w = i % SSMW;
        rows[i] = ssmb[(size_t)(l0 + r)*SSMW4 + w];
    }
    __syncthreads();

    float negA[NS];
    #pragma unroll
    for (int n = 0; n < NS; ++n) negA[n] = -__expf(A_log[d*NS + n]);
    float dtw = dt_w[k*DI + d];
    float dtb = dt_b[k*DI + d];

    float h[NS];
    #pragma unroll
    for (int n = 0; n < NS; ++n) h[n] = 0.f;
    float sumdt = 0.f;

    const float* xcb = xc + (size_t)b*LL*DI;
    for (int li = 0; li < LC; ++li) {
        const float* row = rows + li*SSMW;
        int j = dir_map(k, l0 + li);
        float pre = fmaf(row[0], dtw, dtb);
        float dt = fmaxf(pre, 0.f) + log1pf(__expf(-fabsf(pre)));
        sumdt += dt;
        float xt = xcb[(size_t)j*DI + d];
        float dx = dt * xt;
        #pragma unroll
        for (int n = 0; n < NS; ++n) {
            float dA = __expf(dt * negA[n]);
            h[n] = fmaf(dA, h[n], dx * row[1 + n]);
        }
    }
    float* Hp = Hbuf + ((size_t)idx*DI + d)*NS;
    #pragma unroll
    for (int n = 0; n < NS; ++n) Hp[n] = h[n];
    sdbuf[(size_t)idx*DI + d] = sumdt;
}

// ---------------- Scan phase 2: in-place exclusive prefix across chunks per (k,b,d,n)
__global__ __launch_bounds__(256) void k_scan2(
    float* HS, const float* __restrict__ sdbuf, const float* __restrict__ A_log)
{
    int t = blockIdx.x * 256 + threadIdx.x;  // < 4*2*DI*NS = 24576
    int n = t & (NS-1);
    int d = (t >> 4) % DI;
    int kb = t / (DI*NS);
    float negA = -__expf(A_log[d*NS + n]);
    float s = 0.f;
    for (int c = 0; c < NC; ++c) {
        size_t idx = (size_t)kb*NC + c;
        size_t off = (idx*DI + d)*NS + n;
        float hl = HS[off];
        HS[off] = s;                          // exclusive prefix (incoming state)
        s = fmaf(__expf(negA * sdbuf[idx*DI + d]), s, hl);
    }
}

// ---------------- Scan phase 3: re-scan chunk from incoming state, write y per direction
__global__ __launch_bounds__(DI) void k_scan3(
    const float* __restrict__ ssm, const float* __restrict__ xc,
    const float* __restrict__ A_log, const float* __restrict__ dt_w,
    const float* __restrict__ dt_b, const float* __restrict__ Ds,
    const float* __restrict__ Sbuf, float* __restrict__ ybuf)
{
    int idx = blockIdx.x;
    int c  = idx % NC;
    int kb = idx / NC;
    int b = kb & 1;
    int k = kb >> 1;
    int d = threadIdx.x;

    __shared__ float rows[LC*SSMW];
    const float* ssmb = ssm + (size_t)b*LL*SSMW4 + SSMW*k;
    int l0 = c * LC;
    for (int i = d; i < LC*SSMW; i += DI) {
        int r = i / SSMW, w = i % SSMW;
        rows[i] = ssmb[(size_t)(l0 + r)*SSMW4 + w];
    }
    __syncthreads();

    float negA[NS];
    #pragma unroll
    for (int n = 0; n < NS; ++n) negA[n] = -__expf(A_log[d*NS + n]);
    float dtw = dt_w[k*DI + d];
    float dtb = dt_b[k*DI + d];
    float Dk  = Ds[k*DI + d];

    float h[NS];
    const float* Sp = Sbuf + ((size_t)idx*DI + d)*NS;
    #pragma unroll
    for (int n = 0; n < NS; ++n) h[n] = Sp[n];

    const float* xcb = xc + (size_t)b*LL*DI;
    float* yb = ybuf + ((size_t)k*BB + b)*LL*DI;   // per-direction output
    for (int li = 0; li < LC; ++li) {
        const float* row = rows + li*SSMW;
        int j = dir_map(k, l0 + li);
        float pre = fmaf(row[0], dtw, dtb);
        float dt = fmaxf(pre, 0.f) + log1pf(__expf(-fabsf(pre)));
        float xt = xcb[(size_t)j*DI + d];
        float dx = dt * xt;
        float y = 0.f;
        #pragma unroll
        for (int n = 0; n < NS; ++n) {
            float dA = __expf(dt * negA[n]);
            h[n] = fmaf(dA, h[n], dx * row[1 + n]);
            y = fmaf(h[n], row[17 + n], y);
        }
        y = fmaf(xt, Dk, y);
        yb[(size_t)j*DI + d] = y;     // each (k,b,j,d) written exactly once
    }
}

// ---------------- Kernel F: sum 4 dirs, gate with silu(z), out_proj, + residual (8 pix/block)
__global__ __launch_bounds__(128) void k_out(
    const float* __restrict__ ybuf, const float* __restrict__ siluz,
    const float* __restrict__ Wout, const float* __restrict__ x,
    float* __restrict__ out)
{
    int pix0 = blockIdx.x * 8;
    int t = threadIdx.x;
    __shared__ float prod[8*DI];
    const size_t stride = (size_t)BB*LL*DI;
    for (int i = t; i < 8*DI; i += 128) {
        size_t gi = (size_t)pix0*DI + i;
        float ysum = ybuf[gi] + ybuf[gi+stride] + ybuf[gi+2*stride] + ybuf[gi+3*stride];
        prod[i] = ysum * siluz[gi];
    }
    __syncthreads();
    if (t < CM) {
        float acc[8];
        #pragma unroll
        for (int p = 0; p < 8; ++p) acc[p] = x[(size_t)(pix0+p)*CM + t];
        for (int c = 0; c < DI; ++c) {
            float w = Wout[(size_t)c*CM + t];
            #pragma unroll
            for (int p = 0; p < 8; ++p) acc[p] = fmaf(prod[p*DI+c], w, acc[p]);
        }
        #pragma unroll
        for (int p = 0; p < 8; ++p) out[(size_t)(pix0+p)*CM + t] = acc[p];
    }
}

extern "C" void kernel_launch(void* const* d_in, const int* in_sizes, int n_in,
                              void* d_out, int out_size, void* d_ws, size_t ws_size,
                              hipStream_t stream) {
    const float* x        = (const float*)d_in[0];
    const float* ln_g     = (const float*)d_in[1];
    const float* ln_b     = (const float*)d_in[2];
    const float* in_projw = (const float*)d_in[3];
    const float* conv_w   = (const float*)d_in[4];
    const float* conv_b   = (const float*)d_in[5];
    const float* x_projw  = (const float*)d_in[6];
    const float* dt_w     = (const float*)d_in[7];
    const float* dt_b     = (const float*)d_in[8];
    const float* A_log    = (const float*)d_in[9];
    const float* Ds       = (const float*)d_in[10];
    const float* out_projw= (const float*)d_in[11];
    float* out = (float*)d_out;

    // workspace layout (floats) — ~56.3 MB (sdbuf aliases dead xproj)
    float* ws = (float*)d_ws;
    size_t n192 = (size_t)NPIX * DI;          // 1,204,224
    size_t n132 = (size_t)NPIX * SSMW4;       // 827,904
    size_t nchk = (size_t)4*BB*NC*DI;         // 301,056
    float* xproj = ws;
    float* siluz = xproj + n192;
    float* xc    = siluz + n192;
    float* ssm   = xc + n192;
    float* ybuf  = ssm + n132;                // 4 * n192
    float* Hbuf  = ybuf + 4*n192;             // nchk * NS  (in-place: becomes Sbuf)
    float* sdbuf = xproj;                     // alias: xproj dead after k_conv

    k_ln_inproj<<<NPIX/8, 384, 0, stream>>>(x, ln_g, ln_b, in_projw, xproj, siluz);
    k_conv<<<BB*HH*(WW/8), DI, 0, stream>>>(xproj, conv_w, conv_b, xc);
    k_xproj<<<NPIX/8, 256, 0, stream>>>(xc, x_projw, ssm);
    k_scan1<<<4*BB*NC, DI, 0, stream>>>(ssm, xc, A_log, dt_w, dt_b, Hbuf, sdbuf);
    k_scan2<<<(4*BB*DI*NS)/256, 256, 0, stream>>>(Hbuf, sdbuf, A_log);
    k_scan3<<<4*BB*NC, DI, 0, stream>>>(ssm, xc, A_log, dt_w, dt_b, Ds, Hbuf, ybuf);
    k_out<<<NPIX/8, 128, 0, stream>>>(ybuf, siluz, out_projw, x, out);
}